// Round 4
// baseline (572.542 us; speedup 1.0000x reference)
//
#include <hip/hip_runtime.h>
#include <math.h>

#define NN 50000
#define NE 800000
#define NG 512
#define LRELU 0.2f
#define LN_EPS 1e-5
#define GCAP 128   // max supported in-degree (data Poisson(16), max ~45)
#define NBUCK 256  // stat-reduction buckets

typedef __attribute__((ext_vector_type(8))) short short8;
typedef __attribute__((ext_vector_type(4))) float f32x4;

// ---------------------------------------------------------------- CSR build
__global__ void hist_kernel(const int* __restrict__ dst, int* __restrict__ deg) {
    int e = blockIdx.x * blockDim.x + threadIdx.x;
    if (e < NE) atomicAdd(&deg[dst[e]], 1);
}

__global__ __launch_bounds__(1024) void scan1(const int* __restrict__ deg,
                                              int* __restrict__ excl,
                                              int* __restrict__ bsum, int n) {
    __shared__ int s[1024];
    int tid = threadIdx.x;
    int gid = blockIdx.x * 1024 + tid;
    int v = (gid < n) ? deg[gid] : 0;
    s[tid] = v;
    __syncthreads();
    for (int off = 1; off < 1024; off <<= 1) {
        int t = (tid >= off) ? s[tid - off] : 0;
        __syncthreads();
        s[tid] += t;
        __syncthreads();
    }
    if (gid < n) excl[gid] = s[tid] - v;
    if (tid == 1023) bsum[blockIdx.x] = s[1023];
}

// scan3 with inline exclusive-prefix of bsum (49 blocks -> one wave reduce)
__global__ __launch_bounds__(1024) void scan3(int* __restrict__ row_ptr,
                                              int* __restrict__ cursor,
                                              const int* __restrict__ bsum, int n) {
    __shared__ int sbase;
    int tid = threadIdx.x;
    if (tid < 64) {
        int v = (tid < (int)blockIdx.x) ? bsum[tid] : 0;   // SB=49 <= 64
        #pragma unroll
        for (int off = 32; off > 0; off >>= 1) v += __shfl_xor(v, off, 64);
        if (tid == 0) sbase = v;
    }
    __syncthreads();
    int gid = blockIdx.x * 1024 + tid;
    if (gid < n) {
        int v = row_ptr[gid] + sbase;
        row_ptr[gid] = v;
        cursor[gid] = v;
    }
    if (gid == 0) row_ptr[n] = NE;
}

__global__ void scatter_kernel(const int* __restrict__ src, const int* __restrict__ dst,
                               int* __restrict__ cursor, int* __restrict__ col_src) {
    int e = blockIdx.x * blockDim.x + threadIdx.x;
    if (e < NE) {
        int pos = atomicAdd(&cursor[dst[e]], 1);
        col_src[pos] = src[e];
    }
}

// ---------------------------------------------------------------- weight prep
// W[k][n] fp32  ->  WT_hi[n][k], WT_lo[n][k] bf16 (split: hi=RNE(v), lo=RNE(v-hi))
__device__ inline void split_bf16(float v, ushort& h, ushort& l) {
    unsigned ub = __float_as_uint(v);
    unsigned hh = (ub + 0x7FFFu + ((ub >> 16) & 1u)) >> 16;
    float vh = __uint_as_float(hh << 16);
    float r = v - vh;
    unsigned ur = __float_as_uint(r);
    unsigned ll = (ur + 0x7FFFu + ((ur >> 16) & 1u)) >> 16;
    h = (ushort)hh; l = (ushort)ll;
}

__global__ __launch_bounds__(256) void prep_w(const float* __restrict__ Wl0,
                                              const float* __restrict__ Wr0,
                                              const float* __restrict__ Wl1,
                                              const float* __restrict__ Wr1,
                                              const float* __restrict__ Wl2,
                                              const float* __restrict__ Wr2,
                                              ushort* __restrict__ wt) {
    int id = blockIdx.x * 256 + threadIdx.x;
    const float* W; int K, N, rel; ushort* hi;
    if (id < 65536) {
        W = (id < 32768) ? Wl0 : Wr0;
        rel = id & 32767; K = 128; N = 256;
        hi = wt + ((id < 32768) ? 0 : 65536);
    } else if (id < 98304) {
        int t = id - 65536;
        W = (t < 16384) ? Wl1 : Wr1;
        rel = t & 16383; K = 256; N = 64;
        hi = wt + 131072 + ((t < 16384) ? 0 : 32768);
    } else if (id < 106496) {
        int t = id - 98304;
        W = (t < 4096) ? Wl2 : Wr2;
        rel = t & 4095; K = 64; N = 64;
        hi = wt + 196608 + ((t < 4096) ? 0 : 8192);
    } else return;
    ushort* lo = hi + K * N;
    int n = rel / K, k = rel - n * K;
    ushort h, l;
    split_bf16(W[k * N + n], h, l);
    hi[rel] = h;
    lo[rel] = l;
}

// ---------------------------------------------------------------- MFMA GEMM (split-bf16)
// NCB = number of 64-wide column blocks staged per block (A read once for all).
// Dual-output via blockIdx.y. Optional fused LN+ReLU on A (stats reduced inline
// from the bucketed double sums written by the previous gat kernel).
template<int NCB, bool DOLN>
__global__ __launch_bounds__(256) void gemm_mfma(const float* __restrict__ A,
                                                 const ushort* __restrict__ Bh0,
                                                 const ushort* __restrict__ Bl0,
                                                 const float* __restrict__ bias0,
                                                 float* __restrict__ C0,
                                                 const ushort* __restrict__ Bh1,
                                                 const ushort* __restrict__ Bl1,
                                                 const float* __restrict__ bias1,
                                                 float* __restrict__ C1,
                                                 int M, int Ncol, int K,
                                                 const double* __restrict__ red,
                                                 int Mdiv,
                                                 const float* __restrict__ lng,
                                                 const float* __restrict__ lnb) {
    __shared__ ushort sAh[64][40];   // stride 40 (80 B): 16B-aligned frags, 2-way-max banks
    __shared__ ushort sAl[64][40];
    __shared__ ushort sBh[64 * NCB][40];
    __shared__ ushort sBl[64 * NCB][40];
    __shared__ float sstat[2];
    const ushort* Bhi = blockIdx.y ? Bh1 : Bh0;
    const ushort* Blo = blockIdx.y ? Bl1 : Bl0;
    const float*  bias = blockIdx.y ? bias1 : bias0;
    float*        C = blockIdx.y ? C1 : C0;
    const int tid = threadIdx.x;
    const int row0 = blockIdx.x * 64;
    const int w = tid >> 6, lane = tid & 63;
    const int fm = lane & 15;         // A row / B col within 16-tile
    const int fk = (lane >> 4) * 8;   // k base of the 8-element fragment
    float mu = 0.f, rstd = 0.f;
    if constexpr (DOLN) {
        if (tid < 64) {
            double sa = 0, sb = 0;
            for (int i = lane; i < NBUCK; i += 64) { sa += red[2 * i]; sb += red[2 * i + 1]; }
            #pragma unroll
            for (int off = 32; off > 0; off >>= 1) {
                sa += __shfl_xor(sa, off, 64);
                sb += __shfl_xor(sb, off, 64);
            }
            if (lane == 0) {
                double m_ = sa / Mdiv;
                double v_ = sb / Mdiv - m_ * m_;
                sstat[0] = (float)m_;
                sstat[1] = (float)(1.0 / sqrt(v_ + LN_EPS));
            }
        }
        __syncthreads();
        mu = sstat[0]; rstd = sstat[1];
    }
    f32x4 acc[4 * NCB] = {};

    for (int k0 = 0; k0 < K; k0 += 32) {
        __syncthreads();
        // stage A: 64 rows x 32 k (float4 global loads -> optional LN+ReLU -> split bf16)
        int f = tid;
        #pragma unroll
        for (int it = 0; it < 2; it++, f += 256) {
            int r = f >> 3, kc = (f & 7) * 4;
            int grow = row0 + r;
            float4 v = (grow < M) ? *(const float4*)&A[(size_t)grow * K + k0 + kc]
                                  : make_float4(0.f, 0.f, 0.f, 0.f);
            if constexpr (DOLN) {
                int c0 = k0 + kc;
                v.x = fmaxf((v.x - mu) * rstd * lng[c0 + 0] + lnb[c0 + 0], 0.f);
                v.y = fmaxf((v.y - mu) * rstd * lng[c0 + 1] + lnb[c0 + 1], 0.f);
                v.z = fmaxf((v.z - mu) * rstd * lng[c0 + 2] + lnb[c0 + 2], 0.f);
                v.w = fmaxf((v.w - mu) * rstd * lng[c0 + 3] + lnb[c0 + 3], 0.f);
            }
            ushort4 h, l;
            split_bf16(v.x, h.x, l.x);
            split_bf16(v.y, h.y, l.y);
            split_bf16(v.z, h.z, l.z);
            split_bf16(v.w, h.w, l.w);
            *(ushort4*)&sAh[r][kc] = h;
            *(ushort4*)&sAl[r][kc] = l;
        }
        // stage B: 64*NCB n x 32 k (already bf16, [n][k] row-major stride K)
        int u = tid;
        #pragma unroll
        for (int it = 0; it < 2 * NCB; it++, u += 256) {
            int n = u >> 3, kc = (u & 7) * 4;
            *(ushort4*)&sBh[n][kc] = *(const ushort4*)&Bhi[(size_t)n * K + k0 + kc];
            *(ushort4*)&sBl[n][kc] = *(const ushort4*)&Blo[(size_t)n * K + k0 + kc];
        }
        __syncthreads();
        short8 ah = *(const short8*)&sAh[w * 16 + fm][fk];
        short8 al = *(const short8*)&sAl[w * 16 + fm][fk];
        #pragma unroll
        for (int c = 0; c < 4 * NCB; c++) {
            short8 bh = *(const short8*)&sBh[c * 16 + fm][fk];
            short8 bl = *(const short8*)&sBl[c * 16 + fm][fk];
            acc[c] = __builtin_amdgcn_mfma_f32_16x16x32_bf16(ah, bh, acc[c], 0, 0, 0);
            acc[c] = __builtin_amdgcn_mfma_f32_16x16x32_bf16(al, bh, acc[c], 0, 0, 0);
            acc[c] = __builtin_amdgcn_mfma_f32_16x16x32_bf16(ah, bl, acc[c], 0, 0, 0);
        }
    }
    // epilogue: C/D layout col=lane&15, row=(lane>>4)*4+reg (m89/m91-verified)
    const int orow = w * 16 + (lane >> 4) * 4;
    #pragma unroll
    for (int c = 0; c < 4 * NCB; c++) {
        int col = c * 16 + fm;
        float bv = bias[col];
        #pragma unroll
        for (int r = 0; r < 4; r++) {
            int grow = row0 + orow + r;
            if (grow < M) C[(size_t)grow * Ncol + col] = acc[c][r] + bv;
        }
    }
}

// ---------------------------------------------------------------- DPP 16-lane sum reduce
// Sum across each contiguous 16-lane group via full-rate VALU DPP (no LDS ops):
// quad_perm(xor1), quad_perm(xor2), row_half_mirror, row_mirror.
__device__ inline float dpp_red_add16(float x) {
    x += __int_as_float(__builtin_amdgcn_update_dpp(0, __float_as_int(x), 0xB1, 0xF, 0xF, true));
    x += __int_as_float(__builtin_amdgcn_update_dpp(0, __float_as_int(x), 0x4E, 0xF, 0xF, true));
    x += __int_as_float(__builtin_amdgcn_update_dpp(0, __float_as_int(x), 0x141, 0xF, 0xF, true));
    x += __int_as_float(__builtin_amdgcn_update_dpp(0, __float_as_int(x), 0x140, 0xF, 0xF, true));
    return x;
}

// online-softmax edge update with wave-uniform fast path (no new max in any group)
__device__ inline void gat_upd_fast(const float4& xv, const float4& rxr, const float4& ratt,
                                    float& m, float& sum, float4& acc) {
    float vx = xv.x + rxr.x; vx = fmaxf(vx, vx * LRELU);
    float vy = xv.y + rxr.y; vy = fmaxf(vy, vy * LRELU);
    float vz = xv.z + rxr.z; vz = fmaxf(vz, vz * LRELU);
    float vw = xv.w + rxr.w; vw = fmaxf(vw, vw * LRELU);
    float p = vx * ratt.x;
    p = fmaf(vy, ratt.y, p);
    p = fmaf(vz, ratt.z, p);
    p = fmaf(vw, ratt.w, p);
    p = dpp_red_add16(p);
    if (__all(p <= m)) {
        float e = __expf(p - m);
        sum += e;
        acc.x = fmaf(e, xv.x, acc.x);
        acc.y = fmaf(e, xv.y, acc.y);
        acc.z = fmaf(e, xv.z, acc.z);
        acc.w = fmaf(e, xv.w, acc.w);
    } else {
        float mn = fmaxf(m, p);
        float sc = __expf(m - mn);
        float e  = __expf(p - mn);
        sum = fmaf(sum, sc, e);
        acc.x = fmaf(acc.x, sc, e * xv.x);
        acc.y = fmaf(acc.y, sc, e * xv.y);
        acc.z = fmaf(acc.z, sc, e * xv.z);
        acc.w = fmaf(acc.w, sc, e * xv.w);
        m = mn;
    }
}

// ---------------------------------------------------------------- fused GATv2, H=4 (HC=256)
// One wave per node; single online-softmax state; 4-deep rotating gather
// prefetch (padded scol, no clamp, no register shifting); DPP logit reduce.
__global__ __launch_bounds__(256) void gat4(const float* __restrict__ xl,
                                            const float* __restrict__ xr,
                                            const float* __restrict__ att,
                                            const float* __restrict__ bias,
                                            const int* __restrict__ row_ptr,
                                            const int* __restrict__ col_src,
                                            float* __restrict__ out,
                                            double* __restrict__ red) {
    __shared__ int scol[4][GCAP + 8];
    __shared__ double bs1[4], bs2[4];
    const int tid = threadIdx.x;
    const int w = tid >> 6, lane = tid & 63;
    const int n = blockIdx.x * 4 + w;
    const int base = row_ptr[n];
    int deg = row_ptr[n + 1] - base;
    if (deg > GCAP) deg = GCAP;
    for (int j = lane; j < deg; j += 64) scol[w][j] = col_src[base + j];
    if (deg > 0 && lane < 8) scol[w][deg + lane] = col_src[base + deg - 1];  // pad
    const float4 rxr  = ((const float4*)(xr + (size_t)n * 256))[lane];
    const float4 ratt = ((const float4*)att)[lane];
    __syncthreads();

    float m = -1e30f, sum = 0.f;
    float4 acc = {0.f, 0.f, 0.f, 0.f};
    if (deg > 0) {
        auto LD = [&](int j) {
            return ((const float4*)(xl + (size_t)scol[w][j] * 256))[lane];
        };
        float4 b0 = LD(0), b1 = LD(1), b2 = LD(2), b3 = LD(3);
        int j = 0;
        for (; j + 4 <= deg; j += 4) {
            gat_upd_fast(b0, rxr, ratt, m, sum, acc); b0 = LD(j + 4);
            gat_upd_fast(b1, rxr, ratt, m, sum, acc); b1 = LD(j + 5);
            gat_upd_fast(b2, rxr, ratt, m, sum, acc); b2 = LD(j + 6);
            gat_upd_fast(b3, rxr, ratt, m, sum, acc); b3 = LD(j + 7);
        }
        int r = deg - j;
        if (r > 0) gat_upd_fast(b0, rxr, ratt, m, sum, acc);
        if (r > 1) gat_upd_fast(b1, rxr, ratt, m, sum, acc);
        if (r > 2) gat_upd_fast(b2, rxr, ratt, m, sum, acc);
    }
    float rden = (sum > 0.f) ? 1.f / sum : 0.f;
    float4 bv = ((const float4*)bias)[lane];
    float4 o;
    o.x = fmaf(acc.x, rden, bv.x);
    o.y = fmaf(acc.y, rden, bv.y);
    o.z = fmaf(acc.z, rden, bv.z);
    o.w = fmaf(acc.w, rden, bv.w);
    ((float4*)(out + (size_t)n * 256))[lane] = o;

    // LN stats on raw output -> bucketed double atomics
    float z1 = o.x + o.y + o.z + o.w;
    float z2 = o.x * o.x + o.y * o.y + o.z * o.z + o.w * o.w;
    #pragma unroll
    for (int off = 32; off > 0; off >>= 1) {
        z1 += __shfl_xor(z1, off, 64);
        z2 += __shfl_xor(z2, off, 64);
    }
    if (lane == 0) { bs1[w] = (double)z1; bs2[w] = (double)z2; }
    __syncthreads();
    if (tid == 0) {
        double t1 = bs1[0] + bs1[1] + bs1[2] + bs1[3];
        double t2 = bs2[0] + bs2[1] + bs2[2] + bs2[3];
        int b = (blockIdx.x & (NBUCK - 1)) * 2;
        atomicAdd(&red[b], t1);
        atomicAdd(&red[b + 1], t2);
    }
}

// ---------------------------------------------------------------- fused GATv2, H=1 (HC=64)
// One wave per node; 4 groups of 16 lanes stride edges (4-way ILP); DPP logit
// reduce; 2-slot prefetch per group (padded, no clamp); shfl-butterfly merge.
__global__ __launch_bounds__(256) void gat1(const float* __restrict__ xl,
                                            const float* __restrict__ xr,
                                            const float* __restrict__ att,
                                            const float* __restrict__ bias,
                                            const int* __restrict__ row_ptr,
                                            const int* __restrict__ col_src,
                                            float* __restrict__ out,
                                            double* __restrict__ red) {
    __shared__ int scol[4][GCAP + 16];
    __shared__ double bs1[4], bs2[4];
    const int tid = threadIdx.x;
    const int w = tid >> 6, lane = tid & 63;
    const int n = blockIdx.x * 4 + w;
    const int g = lane >> 4, li = lane & 15;
    const int base = row_ptr[n];
    int deg = row_ptr[n + 1] - base;
    if (deg > GCAP) deg = GCAP;
    for (int j = lane; j < deg; j += 64) scol[w][j] = col_src[base + j];
    if (deg > 0 && lane < 16) scol[w][deg + lane] = col_src[base + deg - 1];  // pad
    const float4 rxr  = ((const float4*)(xr + (size_t)n * 64))[li];
    const float4 ratt = ((const float4*)att)[li];
    __syncthreads();

    float m = -1e30f, sum = 0.f;
    float4 acc = {0.f, 0.f, 0.f, 0.f};
    if (deg > 0) {
        auto LD = [&](int j) {
            return ((const float4*)(xl + (size_t)scol[w][j] * 64))[li];
        };
        float4 a = LD(g), b = LD(g + 4);
        for (int j = g; j < deg; j += 8) {
            gat_upd_fast(a, rxr, ratt, m, sum, acc); a = LD(j + 8);
            if (j + 4 < deg) { gat_upd_fast(b, rxr, ratt, m, sum, acc); b = LD(j + 12); }
        }
    }
    // combine the 4 per-group online-softmax states
    #pragma unroll
    for (int off = 16; off < 64; off <<= 1) {
        float m2 = __shfl_xor(m, off, 64);
        float z2 = __shfl_xor(sum, off, 64);
        float ax = __shfl_xor(acc.x, off, 64);
        float ay = __shfl_xor(acc.y, off, 64);
        float az = __shfl_xor(acc.z, off, 64);
        float aw = __shfl_xor(acc.w, off, 64);
        float M = fmaxf(m, m2);
        float e1 = __expf(m - M), e2 = __expf(m2 - M);
        sum   = sum   * e1 + z2 * e2;
        acc.x = acc.x * e1 + ax * e2;
        acc.y = acc.y * e1 + ay * e2;
        acc.z = acc.z * e1 + az * e2;
        acc.w = acc.w * e1 + aw * e2;
        m = M;
    }
    float rden = (sum > 0.f) ? 1.f / sum : 0.f;
    float4 bv = ((const float4*)bias)[li];
    float4 o;
    o.x = fmaf(acc.x, rden, bv.x);
    o.y = fmaf(acc.y, rden, bv.y);
    o.z = fmaf(acc.z, rden, bv.z);
    o.w = fmaf(acc.w, rden, bv.w);
    if (g == 0) ((float4*)(out + (size_t)n * 64))[li] = o;

    float z1 = (g == 0) ? (o.x + o.y + o.z + o.w) : 0.f;
    float z2 = (g == 0) ? (o.x * o.x + o.y * o.y + o.z * o.z + o.w * o.w) : 0.f;
    #pragma unroll
    for (int off = 32; off > 0; off >>= 1) {
        z1 += __shfl_xor(z1, off, 64);
        z2 += __shfl_xor(z2, off, 64);
    }
    if (lane == 0) { bs1[w] = (double)z1; bs2[w] = (double)z2; }
    __syncthreads();
    if (tid == 0) {
        double t1 = bs1[0] + bs1[1] + bs1[2] + bs1[3];
        double t2 = bs2[0] + bs2[1] + bs2[2] + bs2[3];
        int b = (blockIdx.x & (NBUCK - 1)) * 2;
        atomicAdd(&red[b], t1);
        atomicAdd(&red[b + 1], t2);
    }
}

// ---------------------------------------------------------------- pooling (fused final LN+ReLU+residual) + MLP head
// Inline stat finalize (sets 1,2 of red); batch[] is sorted: each wave walks a
// contiguous node range, flushing atomics only at graph boundaries.
#define PLB 256
__global__ __launch_bounds__(256) void pool_ln(const float* __restrict__ C2,
                                               const float* __restrict__ D,
                                               const double* __restrict__ red,
                                               const float* __restrict__ g1,
                                               const float* __restrict__ b1,
                                               const float* __restrict__ g2,
                                               const float* __restrict__ b2,
                                               const int* __restrict__ batch,
                                               float* __restrict__ Zsum,
                                               int* __restrict__ gcount) {
    __shared__ float sst[4];
    const int w = threadIdx.x >> 6;
    const int lane = threadIdx.x & 63;
    if (w < 2) {   // wave0 -> set1 (layer-1 stats), wave1 -> set2 (layer-2 stats)
        const double* rp = red + (w + 1) * 2 * NBUCK;
        double sa = 0, sb = 0;
        for (int i = lane; i < NBUCK; i += 64) { sa += rp[2 * i]; sb += rp[2 * i + 1]; }
        #pragma unroll
        for (int off = 32; off > 0; off >>= 1) {
            sa += __shfl_xor(sa, off, 64);
            sb += __shfl_xor(sb, off, 64);
        }
        if (lane == 0) {
            double m_ = sa / (double)(NN * 64);
            double v_ = sb / (double)(NN * 64) - m_ * m_;
            sst[w * 2]     = (float)m_;
            sst[w * 2 + 1] = (float)(1.0 / sqrt(v_ + LN_EPS));
        }
    }
    __syncthreads();
    const float mu1 = sst[0], r1 = sst[1], mu2 = sst[2], r2 = sst[3];
    const int wid = blockIdx.x * 4 + w;
    const int NW = PLB * 4;
    const int per = (NN + NW - 1) / NW;
    int n0 = wid * per;
    int n1 = n0 + per; if (n1 > NN) n1 = NN;
    if (n0 >= n1) return;
    const float ga = r1 * g1[lane], ba = fmaf(-mu1, ga, b1[lane]);
    const float gb = r2 * g2[lane], bb = fmaf(-mu2, gb, b2[lane]);
    float zacc = 0.f; int cnt = 0; int cur = batch[n0];
    for (int n = n0; n < n1; n++) {
        int gi = batch[n];
        if (gi != cur) {
            atomicAdd(&Zsum[cur * 64 + lane], zacc);
            if (lane == 0) atomicAdd(&gcount[cur], cnt);
            zacc = 0.f; cnt = 0; cur = gi;
        }
        float hin = fmaxf(fmaf(D[(size_t)n * 64 + lane], ga, ba), 0.f);   // relu(ln1(D)) residual
        float v = fmaxf(fmaf(C2[(size_t)n * 64 + lane], gb, bb), 0.f) + hin;
        zacc += v; cnt++;
    }
    atomicAdd(&Zsum[cur * 64 + lane], zacc);
    if (lane == 0) atomicAdd(&gcount[cur], cnt);
}

__global__ __launch_bounds__(64) void mlp_head(const float* __restrict__ Zsum,
                                               const int* __restrict__ gcount,
                                               const float* __restrict__ Wh1,
                                               const float* __restrict__ bh1,
                                               const float* __restrict__ Wh2,
                                               const float* __restrict__ bh2,
                                               float* __restrict__ out) {
    __shared__ float sz[64];
    int g = blockIdx.x, tid = threadIdx.x;
    int cnt = gcount[g];
    float inv = 1.f / (float)(cnt > 1 ? cnt : 1);
    sz[tid] = Zsum[g * 64 + tid] * inv;
    __syncthreads();
    float acc = bh1[tid];
    #pragma unroll
    for (int c = 0; c < 64; c++) acc = fmaf(sz[c], Wh1[c * 64 + tid], acc);
    acc = fmaxf(acc, 0.f);
    float v = acc * Wh2[tid];
    #pragma unroll
    for (int off = 32; off > 0; off >>= 1) v += __shfl_xor(v, off, 64);
    if (tid == 0) out[g] = v + bh2[0];
}

// ---------------------------------------------------------------- launch
extern "C" void kernel_launch(void* const* d_in, const int* in_sizes, int n_in,
                              void* d_out, int out_size, void* d_ws, size_t ws_size,
                              hipStream_t stream) {
    (void)in_sizes; (void)n_in; (void)out_size; (void)ws_size;
    const float* x     = (const float*)d_in[0];
    const int*   ei    = (const int*)d_in[1];
    const int*   batch = (const int*)d_in[2];
    const float* Wl0 = (const float*)d_in[3];  const float* bl0 = (const float*)d_in[4];
    const float* Wr0 = (const float*)d_in[5];  const float* br0 = (const float*)d_in[6];
    const float* at0 = (const float*)d_in[7];  const float* bi0 = (const float*)d_in[8];
    const float* lg0 = (const float*)d_in[9];  const float* lb0 = (const float*)d_in[10];
    const float* Wl1 = (const float*)d_in[11]; const float* bl1 = (const float*)d_in[12];
    const float* Wr1 = (const float*)d_in[13]; const float* br1 = (const float*)d_in[14];
    const float* at1 = (const float*)d_in[15]; const float* bi1 = (const float*)d_in[16];
    const float* lg1 = (const float*)d_in[17]; const float* lb1 = (const float*)d_in[18];
    const float* Wl2 = (const float*)d_in[19]; const float* bl2 = (const float*)d_in[20];
    const float* Wr2 = (const float*)d_in[21]; const float* br2 = (const float*)d_in[22];
    const float* at2 = (const float*)d_in[23]; const float* bi2 = (const float*)d_in[24];
    const float* lg2 = (const float*)d_in[25]; const float* lb2 = (const float*)d_in[26];
    const float* Wh1 = (const float*)d_in[27]; const float* bh1 = (const float*)d_in[28];
    const float* Wh2 = (const float*)d_in[29]; const float* bh2 = (const float*)d_in[30];
    float* out = (float*)d_out;

    const int* srcp = ei;
    const int* dstp = ei + NE;

    char* w = (char*)d_ws;
    size_t off = 0;
    auto carve = [&](size_t bytes) -> void* {
        void* p = w + off;
        off += (bytes + 255) & ~(size_t)255;
        return p;
    };
    float* A = (float*)carve((size_t)NN * 256 * 4);   // xl
    float* B = (float*)carve((size_t)NN * 256 * 4);   // xr
    float* C = (float*)carve((size_t)NN * 256 * 4);   // h1 raw / h3 raw
    float* D = (float*)carve((size_t)NN * 64 * 4);    // h2 raw
    ushort* wt = (ushort*)carve(212992 * 2);          // split-bf16 transposed weights
    const size_t REDB = (size_t)3 * NBUCK * 2 * sizeof(double);   // 3 bucket sets
    size_t zbytes = REDB + (size_t)NG * 64 * 4 + NG * 4 + (size_t)NN * 4;
    char* zb = (char*)carve(zbytes);
    double* red   = (double*)zb;
    float*  Zsum  = (float*)(zb + REDB);
    int*    gcnt  = (int*)(zb + REDB + (size_t)NG * 64 * 4);
    int*    deg   = (int*)(zb + REDB + (size_t)NG * 64 * 4 + NG * 4);
    int* row_ptr = (int*)carve((size_t)(NN + 1) * 4);
    int* cursor  = (int*)carve((size_t)NN * 4);
    int* col_src = (int*)carve((size_t)NE * 4);
    int* bsum    = (int*)carve(64 * 4);

    const ushort* W0lh = wt;           const ushort* W0ll = wt + 32768;
    const ushort* W0rh = wt + 65536;   const ushort* W0rl = wt + 98304;
    const ushort* W1lh = wt + 131072;  const ushort* W1ll = wt + 147456;
    const ushort* W1rh = wt + 163840;  const ushort* W1rl = wt + 180224;
    const ushort* W2lh = wt + 196608;  const ushort* W2ll = wt + 200704;
    const ushort* W2rh = wt + 204800;  const ushort* W2rl = wt + 208896;

    hipMemsetAsync(zb, 0, zbytes, stream);
    prep_w<<<416, 256, 0, stream>>>(Wl0, Wr0, Wl1, Wr1, Wl2, Wr2, wt);

    // CSR build (sort edges by dst)
    hist_kernel<<<(NE + 255) / 256, 256, 0, stream>>>(dstp, deg);
    const int SB = (NN + 1023) / 1024;  // 49
    scan1<<<SB, 1024, 0, stream>>>(deg, row_ptr, bsum, NN);
    scan3<<<SB, 1024, 0, stream>>>(row_ptr, cursor, bsum, NN);
    scatter_kernel<<<(NE + 255) / 256, 256, 0, stream>>>(srcp, dstp, cursor, col_src);

    const int GR = (NN + 63) / 64;     // 782 (gemm row blocks)
    const int GATB = NN / 4;           // 12500 (4 nodes/block, wave-per-node)

    // ---- layer 0: 128 -> 4x64 (all 256 cols per block: A read once; dual via blockIdx.y)
    gemm_mfma<4, false><<<dim3(GR, 2), 256, 0, stream>>>(x, W0lh, W0ll, bl0, A,
                                                         W0rh, W0rl, br0, B, NN, 256, 128,
                                                         nullptr, 1, nullptr, nullptr);
    gat4<<<GATB, 256, 0, stream>>>(A, B, at0, bi0, row_ptr, col_src, C, red);

    // ---- layer 1: 256 -> 64 (LN0+ReLU fused into GEMM A-staging, stats inline from red)
    gemm_mfma<1, true><<<dim3(GR, 2), 256, 0, stream>>>(C, W1lh, W1ll, bl1, A,
                                                        W1rh, W1rl, br1, B, NN, 64, 256,
                                                        red, NN * 256, lg0, lb0);
    gat1<<<GATB, 256, 0, stream>>>(A, B, at1, bi1, row_ptr, col_src, D, red + 2 * NBUCK);

    // ---- layer 2: 64 -> 64 (LN1+ReLU fused into GEMM A-staging)
    gemm_mfma<1, true><<<dim3(GR, 2), 256, 0, stream>>>(D, W2lh, W2ll, bl2, A,
                                                        W2rh, W2rl, br2, B, NN, 64, 64,
                                                        red + 2 * NBUCK, NN * 64, lg1, lb1);
    gat1<<<GATB, 256, 0, stream>>>(A, B, at2, bi2, row_ptr, col_src, C, red + 4 * NBUCK);

    // ---- pool (inline stats + fused LN+ReLU+residual, boundary-flush atomics) + MLP head
    pool_ln<<<PLB, 256, 0, stream>>>(C, D, red, lg1, lb1, lg2, lb2,
                                     batch, Zsum, gcnt);
    mlp_head<<<NG, 64, 0, stream>>>(Zsum, gcnt, Wh1, bh1, Wh2, bh2, out);
}

// Round 5
// 546.588 us; speedup vs baseline: 1.0475x; 1.0475x over previous
//
#include <hip/hip_runtime.h>
#include <math.h>

#define NN 50000
#define NE 800000
#define NG 512
#define LRELU 0.2f
#define LN_EPS 1e-5
#define GCAP 128   // max supported in-degree (data Poisson(16), max ~45)
#define NBUCK 256  // stat-reduction buckets

typedef __attribute__((ext_vector_type(8))) short short8;
typedef __attribute__((ext_vector_type(4))) float f32x4;

// ---------------------------------------------------------------- CSR build
__global__ void hist_kernel(const int* __restrict__ dst, int* __restrict__ deg) {
    int e = blockIdx.x * blockDim.x + threadIdx.x;
    if (e < NE) atomicAdd(&deg[dst[e]], 1);
}

__global__ __launch_bounds__(1024) void scan1(const int* __restrict__ deg,
                                              int* __restrict__ excl,
                                              int* __restrict__ bsum, int n) {
    __shared__ int s[1024];
    int tid = threadIdx.x;
    int gid = blockIdx.x * 1024 + tid;
    int v = (gid < n) ? deg[gid] : 0;
    s[tid] = v;
    __syncthreads();
    for (int off = 1; off < 1024; off <<= 1) {
        int t = (tid >= off) ? s[tid - off] : 0;
        __syncthreads();
        s[tid] += t;
        __syncthreads();
    }
    if (gid < n) excl[gid] = s[tid] - v;
    if (tid == 1023) bsum[blockIdx.x] = s[1023];
}

// scan3 with inline exclusive-prefix of bsum (49 blocks -> one wave reduce)
__global__ __launch_bounds__(1024) void scan3(int* __restrict__ row_ptr,
                                              int* __restrict__ cursor,
                                              const int* __restrict__ bsum, int n) {
    __shared__ int sbase;
    int tid = threadIdx.x;
    if (tid < 64) {
        int v = (tid < (int)blockIdx.x) ? bsum[tid] : 0;   // SB=49 <= 64
        #pragma unroll
        for (int off = 32; off > 0; off >>= 1) v += __shfl_xor(v, off, 64);
        if (tid == 0) sbase = v;
    }
    __syncthreads();
    int gid = blockIdx.x * 1024 + tid;
    if (gid < n) {
        int v = row_ptr[gid] + sbase;
        row_ptr[gid] = v;
        cursor[gid] = v;
    }
    if (gid == 0) row_ptr[n] = NE;
}

__global__ void scatter_kernel(const int* __restrict__ src, const int* __restrict__ dst,
                               int* __restrict__ cursor, int* __restrict__ col_src) {
    int e = blockIdx.x * blockDim.x + threadIdx.x;
    if (e < NE) {
        int pos = atomicAdd(&cursor[dst[e]], 1);
        col_src[pos] = src[e];
    }
}

// ---------------------------------------------------------------- weight prep
// W[k][n] fp32  ->  WT_hi[n][k], WT_lo[n][k] bf16 (split: hi=RNE(v), lo=RNE(v-hi))
__device__ inline void split_bf16(float v, ushort& h, ushort& l) {
    unsigned ub = __float_as_uint(v);
    unsigned hh = (ub + 0x7FFFu + ((ub >> 16) & 1u)) >> 16;
    float vh = __uint_as_float(hh << 16);
    float r = v - vh;
    unsigned ur = __float_as_uint(r);
    unsigned ll = (ur + 0x7FFFu + ((ur >> 16) & 1u)) >> 16;
    h = (ushort)hh; l = (ushort)ll;
}

__global__ __launch_bounds__(256) void prep_w(const float* __restrict__ Wl0,
                                              const float* __restrict__ Wr0,
                                              const float* __restrict__ Wl1,
                                              const float* __restrict__ Wr1,
                                              const float* __restrict__ Wl2,
                                              const float* __restrict__ Wr2,
                                              ushort* __restrict__ wt) {
    int id = blockIdx.x * 256 + threadIdx.x;
    const float* W; int K, N, rel; ushort* hi;
    if (id < 65536) {
        W = (id < 32768) ? Wl0 : Wr0;
        rel = id & 32767; K = 128; N = 256;
        hi = wt + ((id < 32768) ? 0 : 65536);
    } else if (id < 98304) {
        int t = id - 65536;
        W = (t < 16384) ? Wl1 : Wr1;
        rel = t & 16383; K = 256; N = 64;
        hi = wt + 131072 + ((t < 16384) ? 0 : 32768);
    } else if (id < 106496) {
        int t = id - 98304;
        W = (t < 4096) ? Wl2 : Wr2;
        rel = t & 4095; K = 64; N = 64;
        hi = wt + 196608 + ((t < 4096) ? 0 : 8192);
    } else return;
    ushort* lo = hi + K * N;
    int n = rel / K, k = rel - n * K;
    ushort h, l;
    split_bf16(W[k * N + n], h, l);
    hi[rel] = h;
    lo[rel] = l;
}

// ---------------------------------------------------------------- MFMA GEMM (split-bf16)
// NCB = 64-wide column blocks staged per block.
// DUAL=false: blockIdx.y selects output set (Bh0.. or Bh1..); cols = 64*NCB of one set.
// DUAL=true : single launch computes BOTH sets; first 32*NCB B-rows from set0 -> C0,
//             rest from set1 -> C1 (A staged/read once for both).
// DOLN: fused relu((a-mu)*rstd*g+b) on A, stats reduced inline from bucketed sums.
template<int NCB, bool DUAL, bool DOLN>
__global__ __launch_bounds__(256) void gemm_mfma(const float* __restrict__ A,
                                                 const ushort* __restrict__ Bh0,
                                                 const ushort* __restrict__ Bl0,
                                                 const float* __restrict__ bias0,
                                                 float* __restrict__ C0,
                                                 const ushort* __restrict__ Bh1,
                                                 const ushort* __restrict__ Bl1,
                                                 const float* __restrict__ bias1,
                                                 float* __restrict__ C1,
                                                 int M, int Ncol, int K,
                                                 const double* __restrict__ red,
                                                 int Mdiv,
                                                 const float* __restrict__ lng,
                                                 const float* __restrict__ lnb) {
    __shared__ ushort sAh[64][40];   // stride 40 (80 B): 16B-aligned frags, 2-way-max banks
    __shared__ ushort sAl[64][40];
    __shared__ ushort sBh[64 * NCB][40];
    __shared__ ushort sBl[64 * NCB][40];
    __shared__ float sstat[2];
    const ushort* Bhi = (!DUAL && blockIdx.y) ? Bh1 : Bh0;
    const ushort* Blo = (!DUAL && blockIdx.y) ? Bl1 : Bl0;
    const float*  biasS = (!DUAL && blockIdx.y) ? bias1 : bias0;
    float*        CS = (!DUAL && blockIdx.y) ? C1 : C0;
    const int tid = threadIdx.x;
    const int row0 = blockIdx.x * 64;
    const int w = tid >> 6, lane = tid & 63;
    const int fm = lane & 15;         // A row / B col within 16-tile
    const int fk = (lane >> 4) * 8;   // k base of the 8-element fragment
    float mu = 0.f, rstd = 0.f;
    if constexpr (DOLN) {
        if (tid < 64) {
            double sa = 0, sb = 0;
            for (int i = lane; i < NBUCK; i += 64) { sa += red[2 * i]; sb += red[2 * i + 1]; }
            #pragma unroll
            for (int off = 32; off > 0; off >>= 1) {
                sa += __shfl_xor(sa, off, 64);
                sb += __shfl_xor(sb, off, 64);
            }
            if (lane == 0) {
                double m_ = sa / Mdiv;
                double v_ = sb / Mdiv - m_ * m_;
                sstat[0] = (float)m_;
                sstat[1] = (float)(1.0 / sqrt(v_ + LN_EPS));
            }
        }
        __syncthreads();
        mu = sstat[0]; rstd = sstat[1];
    }
    f32x4 acc[4 * NCB] = {};

    for (int k0 = 0; k0 < K; k0 += 32) {
        __syncthreads();
        // stage A: 64 rows x 32 k (float4 global loads -> optional LN+ReLU -> split bf16)
        int f = tid;
        #pragma unroll
        for (int it = 0; it < 2; it++, f += 256) {
            int r = f >> 3, kc = (f & 7) * 4;
            int grow = row0 + r;
            float4 v = (grow < M) ? *(const float4*)&A[(size_t)grow * K + k0 + kc]
                                  : make_float4(0.f, 0.f, 0.f, 0.f);
            if constexpr (DOLN) {
                int c0 = k0 + kc;
                v.x = fmaxf((v.x - mu) * rstd * lng[c0 + 0] + lnb[c0 + 0], 0.f);
                v.y = fmaxf((v.y - mu) * rstd * lng[c0 + 1] + lnb[c0 + 1], 0.f);
                v.z = fmaxf((v.z - mu) * rstd * lng[c0 + 2] + lnb[c0 + 2], 0.f);
                v.w = fmaxf((v.w - mu) * rstd * lng[c0 + 3] + lnb[c0 + 3], 0.f);
            }
            ushort4 h, l;
            split_bf16(v.x, h.x, l.x);
            split_bf16(v.y, h.y, l.y);
            split_bf16(v.z, h.z, l.z);
            split_bf16(v.w, h.w, l.w);
            *(ushort4*)&sAh[r][kc] = h;
            *(ushort4*)&sAl[r][kc] = l;
        }
        // stage B: 64*NCB n x 32 k (already bf16, [n][k] row-major stride K)
        int u = tid;
        #pragma unroll
        for (int it = 0; it < 2 * NCB; it++, u += 256) {
            int n = u >> 3, kc = (u & 7) * 4;
            const ushort* ph; const ushort* pl; int nr;
            if constexpr (DUAL) {
                bool s1 = n >= (32 * NCB);
                ph = s1 ? Bh1 : Bh0; pl = s1 ? Bl1 : Bl0;
                nr = s1 ? n - 32 * NCB : n;
            } else {
                ph = Bhi; pl = Blo; nr = n;
            }
            *(ushort4*)&sBh[n][kc] = *(const ushort4*)&ph[(size_t)nr * K + k0 + kc];
            *(ushort4*)&sBl[n][kc] = *(const ushort4*)&pl[(size_t)nr * K + k0 + kc];
        }
        __syncthreads();
        short8 ah = *(const short8*)&sAh[w * 16 + fm][fk];
        short8 al = *(const short8*)&sAl[w * 16 + fm][fk];
        #pragma unroll
        for (int c = 0; c < 4 * NCB; c++) {
            short8 bh = *(const short8*)&sBh[c * 16 + fm][fk];
            short8 bl = *(const short8*)&sBl[c * 16 + fm][fk];
            acc[c] = __builtin_amdgcn_mfma_f32_16x16x32_bf16(ah, bh, acc[c], 0, 0, 0);
            acc[c] = __builtin_amdgcn_mfma_f32_16x16x32_bf16(al, bh, acc[c], 0, 0, 0);
            acc[c] = __builtin_amdgcn_mfma_f32_16x16x32_bf16(ah, bl, acc[c], 0, 0, 0);
        }
    }
    // epilogue: C/D layout col=lane&15, row=(lane>>4)*4+reg (m89/m91-verified)
    const int orow = w * 16 + (lane >> 4) * 4;
    #pragma unroll
    for (int c = 0; c < 4 * NCB; c++) {
        float* Cp; const float* bp; int col;
        if constexpr (DUAL) {
            bool s1 = c >= 2 * NCB;
            Cp = s1 ? C1 : C0; bp = s1 ? bias1 : bias0;
            col = (s1 ? c - 2 * NCB : c) * 16 + fm;
        } else {
            Cp = CS; bp = biasS;
            col = c * 16 + fm;
        }
        float bv = bp[col];
        #pragma unroll
        for (int r = 0; r < 4; r++) {
            int grow = row0 + orow + r;
            if (grow < M) Cp[(size_t)grow * Ncol + col] = acc[c][r] + bv;
        }
    }
}

// ---------------------------------------------------------------- DPP 16-lane sum reduce
// Sum across each contiguous 16-lane group via full-rate VALU DPP (no LDS ops):
// quad_perm(xor1), quad_perm(xor2), row_half_mirror, row_mirror.
__device__ inline float dpp_red_add16(float x) {
    x += __int_as_float(__builtin_amdgcn_update_dpp(0, __float_as_int(x), 0xB1, 0xF, 0xF, true));
    x += __int_as_float(__builtin_amdgcn_update_dpp(0, __float_as_int(x), 0x4E, 0xF, 0xF, true));
    x += __int_as_float(__builtin_amdgcn_update_dpp(0, __float_as_int(x), 0x141, 0xF, 0xF, true));
    x += __int_as_float(__builtin_amdgcn_update_dpp(0, __float_as_int(x), 0x140, 0xF, 0xF, true));
    return x;
}

// online-softmax edge update with wave-uniform fast path (no new max in any group)
__device__ inline void gat_upd_fast(const float4& xv, const float4& rxr, const float4& ratt,
                                    float& m, float& sum, float4& acc) {
    float vx = xv.x + rxr.x; vx = fmaxf(vx, vx * LRELU);
    float vy = xv.y + rxr.y; vy = fmaxf(vy, vy * LRELU);
    float vz = xv.z + rxr.z; vz = fmaxf(vz, vz * LRELU);
    float vw = xv.w + rxr.w; vw = fmaxf(vw, vw * LRELU);
    float p = vx * ratt.x;
    p = fmaf(vy, ratt.y, p);
    p = fmaf(vz, ratt.z, p);
    p = fmaf(vw, ratt.w, p);
    p = dpp_red_add16(p);
    if (__all(p <= m)) {
        float e = __expf(p - m);
        sum += e;
        acc.x = fmaf(e, xv.x, acc.x);
        acc.y = fmaf(e, xv.y, acc.y);
        acc.z = fmaf(e, xv.z, acc.z);
        acc.w = fmaf(e, xv.w, acc.w);
    } else {
        float mn = fmaxf(m, p);
        float sc = __expf(m - mn);
        float e  = __expf(p - mn);
        sum = fmaf(sum, sc, e);
        acc.x = fmaf(acc.x, sc, e * xv.x);
        acc.y = fmaf(acc.y, sc, e * xv.y);
        acc.z = fmaf(acc.z, sc, e * xv.z);
        acc.w = fmaf(acc.w, sc, e * xv.w);
        m = mn;
    }
}

// ---------------------------------------------------------------- fused GATv2, H=4 (HC=256)
// One wave per node; single online-softmax state; 2-deep gather prefetch;
// DPP logit reduce; bucketed LN-stat atomics.
__global__ __launch_bounds__(256) void gat4(const float* __restrict__ xl,
                                            const float* __restrict__ xr,
                                            const float* __restrict__ att,
                                            const float* __restrict__ bias,
                                            const int* __restrict__ row_ptr,
                                            const int* __restrict__ col_src,
                                            float* __restrict__ out,
                                            double* __restrict__ red) {
    __shared__ int scol[4][GCAP];
    __shared__ double bs1[4], bs2[4];
    const int tid = threadIdx.x;
    const int w = tid >> 6, lane = tid & 63;
    const int n = blockIdx.x * 4 + w;
    const int base = row_ptr[n];
    int deg = row_ptr[n + 1] - base;
    if (deg > GCAP) deg = GCAP;
    for (int j = lane; j < deg; j += 64) scol[w][j] = col_src[base + j];
    const float4 rxr  = ((const float4*)(xr + (size_t)n * 256))[lane];
    const float4 ratt = ((const float4*)att)[lane];
    __syncthreads();

    float m = -1e30f, sum = 0.f;
    float4 acc = {0.f, 0.f, 0.f, 0.f};
    if (deg > 0) {
        const int dm1 = deg - 1;
        float4 xv0 = ((const float4*)(xl + (size_t)scol[w][0] * 256))[lane];
        float4 xv1 = ((const float4*)(xl + (size_t)scol[w][(1 < dm1) ? 1 : dm1] * 256))[lane];
        for (int j = 0; j < deg; j++) {
            float4 xv = xv0;
            xv0 = xv1;
            int idx = (j + 2 < deg) ? j + 2 : dm1;   // clamped (redundant loads hit cache)
            xv1 = ((const float4*)(xl + (size_t)scol[w][idx] * 256))[lane];
            gat_upd_fast(xv, rxr, ratt, m, sum, acc);
        }
    }
    float rden = (sum > 0.f) ? 1.f / sum : 0.f;
    float4 bv = ((const float4*)bias)[lane];
    float4 o;
    o.x = fmaf(acc.x, rden, bv.x);
    o.y = fmaf(acc.y, rden, bv.y);
    o.z = fmaf(acc.z, rden, bv.z);
    o.w = fmaf(acc.w, rden, bv.w);
    ((float4*)(out + (size_t)n * 256))[lane] = o;

    // LN stats on raw output -> bucketed double atomics
    float z1 = o.x + o.y + o.z + o.w;
    float z2 = o.x * o.x + o.y * o.y + o.z * o.z + o.w * o.w;
    #pragma unroll
    for (int off = 32; off > 0; off >>= 1) {
        z1 += __shfl_xor(z1, off, 64);
        z2 += __shfl_xor(z2, off, 64);
    }
    if (lane == 0) { bs1[w] = (double)z1; bs2[w] = (double)z2; }
    __syncthreads();
    if (tid == 0) {
        double t1 = bs1[0] + bs1[1] + bs1[2] + bs1[3];
        double t2 = bs2[0] + bs2[1] + bs2[2] + bs2[3];
        int b = (blockIdx.x & (NBUCK - 1)) * 2;
        atomicAdd(&red[b], t1);
        atomicAdd(&red[b + 1], t2);
    }
}

// ---------------------------------------------------------------- fused GATv2, H=1 (HC=64)
// One wave per node; 4 groups of 16 lanes stride edges (4-way ILP); DPP logit
// reduce; 2-deep prefetch per group; states merged via shfl butterfly.
__global__ __launch_bounds__(256) void gat1(const float* __restrict__ xl,
                                            const float* __restrict__ xr,
                                            const float* __restrict__ att,
                                            const float* __restrict__ bias,
                                            const int* __restrict__ row_ptr,
                                            const int* __restrict__ col_src,
                                            float* __restrict__ out,
                                            double* __restrict__ red) {
    __shared__ int scol[4][GCAP];
    __shared__ double bs1[4], bs2[4];
    const int tid = threadIdx.x;
    const int w = tid >> 6, lane = tid & 63;
    const int n = blockIdx.x * 4 + w;
    const int g = lane >> 4, li = lane & 15;
    const int base = row_ptr[n];
    int deg = row_ptr[n + 1] - base;
    if (deg > GCAP) deg = GCAP;
    for (int j = lane; j < deg; j += 64) scol[w][j] = col_src[base + j];
    const float4 rxr  = ((const float4*)(xr + (size_t)n * 64))[li];
    const float4 ratt = ((const float4*)att)[li];
    __syncthreads();

    float m = -1e30f, sum = 0.f;
    float4 acc = {0.f, 0.f, 0.f, 0.f};
    if (deg > 0) {
        const int dm1 = deg - 1;
        auto Lg = [&](int j) {
            int idx = (j < dm1) ? j : dm1;
            return ((const float4*)(xl + (size_t)scol[w][idx] * 64))[li];
        };
        float4 xv0 = Lg(g), xv1 = Lg(g + 4);
        for (int j = g; j < deg; j += 4) {
            float4 xv = xv0;
            xv0 = xv1;
            xv1 = Lg(j + 8);
            gat_upd_fast(xv, rxr, ratt, m, sum, acc);
        }
    }
    // combine the 4 per-group online-softmax states
    #pragma unroll
    for (int off = 16; off < 64; off <<= 1) {
        float m2 = __shfl_xor(m, off, 64);
        float z2 = __shfl_xor(sum, off, 64);
        float ax = __shfl_xor(acc.x, off, 64);
        float ay = __shfl_xor(acc.y, off, 64);
        float az = __shfl_xor(acc.z, off, 64);
        float aw = __shfl_xor(acc.w, off, 64);
        float M = fmaxf(m, m2);
        float e1 = __expf(m - M), e2 = __expf(m2 - M);
        sum   = sum   * e1 + z2 * e2;
        acc.x = acc.x * e1 + ax * e2;
        acc.y = acc.y * e1 + ay * e2;
        acc.z = acc.z * e1 + az * e2;
        acc.w = acc.w * e1 + aw * e2;
        m = M;
    }
    float rden = (sum > 0.f) ? 1.f / sum : 0.f;
    float4 bv = ((const float4*)bias)[li];
    float4 o;
    o.x = fmaf(acc.x, rden, bv.x);
    o.y = fmaf(acc.y, rden, bv.y);
    o.z = fmaf(acc.z, rden, bv.z);
    o.w = fmaf(acc.w, rden, bv.w);
    if (g == 0) ((float4*)(out + (size_t)n * 64))[li] = o;

    float z1 = (g == 0) ? (o.x + o.y + o.z + o.w) : 0.f;
    float z2 = (g == 0) ? (o.x * o.x + o.y * o.y + o.z * o.z + o.w * o.w) : 0.f;
    #pragma unroll
    for (int off = 32; off > 0; off >>= 1) {
        z1 += __shfl_xor(z1, off, 64);
        z2 += __shfl_xor(z2, off, 64);
    }
    if (lane == 0) { bs1[w] = (double)z1; bs2[w] = (double)z2; }
    __syncthreads();
    if (tid == 0) {
        double t1 = bs1[0] + bs1[1] + bs1[2] + bs1[3];
        double t2 = bs2[0] + bs2[1] + bs2[2] + bs2[3];
        int b = (blockIdx.x & (NBUCK - 1)) * 2;
        atomicAdd(&red[b], t1);
        atomicAdd(&red[b + 1], t2);
    }
}

// ---------------------------------------------------------------- pooling (fused final LN+ReLU+residual) + MLP head
// Inline stat finalize; batch[] is sorted: each wave walks a contiguous node
// range, flushing atomics only at graph boundaries.
#define PLB 256
__global__ __launch_bounds__(256) void pool_ln(const float* __restrict__ C2,
                                               const float* __restrict__ D,
                                               const double* __restrict__ red,
                                               const float* __restrict__ g1,
                                               const float* __restrict__ b1,
                                               const float* __restrict__ g2,
                                               const float* __restrict__ b2,
                                               const int* __restrict__ batch,
                                               float* __restrict__ Zsum,
                                               int* __restrict__ gcount) {
    __shared__ float sst[4];
    const int w = threadIdx.x >> 6;
    const int lane = threadIdx.x & 63;
    if (w < 2) {   // wave0 -> set1 (layer-1 stats), wave1 -> set2 (layer-2 stats)
        const double* rp = red + (w + 1) * 2 * NBUCK;
        double sa = 0, sb = 0;
        for (int i = lane; i < NBUCK; i += 64) { sa += rp[2 * i]; sb += rp[2 * i + 1]; }
        #pragma unroll
        for (int off = 32; off > 0; off >>= 1) {
            sa += __shfl_xor(sa, off, 64);
            sb += __shfl_xor(sb, off, 64);
        }
        if (lane == 0) {
            double m_ = sa / (double)(NN * 64);
            double v_ = sb / (double)(NN * 64) - m_ * m_;
            sst[w * 2]     = (float)m_;
            sst[w * 2 + 1] = (float)(1.0 / sqrt(v_ + LN_EPS));
        }
    }
    __syncthreads();
    const float mu1 = sst[0], r1 = sst[1], mu2 = sst[2], r2 = sst[3];
    const int wid = blockIdx.x * 4 + w;
    const int NW = PLB * 4;
    const int per = (NN + NW - 1) / NW;
    int n0 = wid * per;
    int n1 = n0 + per; if (n1 > NN) n1 = NN;
    if (n0 >= n1) return;
    const float ga = r1 * g1[lane], ba = fmaf(-mu1, ga, b1[lane]);
    const float gb = r2 * g2[lane], bb = fmaf(-mu2, gb, b2[lane]);
    float zacc = 0.f; int cnt = 0; int cur = batch[n0];
    for (int n = n0; n < n1; n++) {
        int gi = batch[n];
        if (gi != cur) {
            atomicAdd(&Zsum[cur * 64 + lane], zacc);
            if (lane == 0) atomicAdd(&gcount[cur], cnt);
            zacc = 0.f; cnt = 0; cur = gi;
        }
        float hin = fmaxf(fmaf(D[(size_t)n * 64 + lane], ga, ba), 0.f);   // relu(ln1(D)) residual
        float v = fmaxf(fmaf(C2[(size_t)n * 64 + lane], gb, bb), 0.f) + hin;
        zacc += v; cnt++;
    }
    atomicAdd(&Zsum[cur * 64 + lane], zacc);
    if (lane == 0) atomicAdd(&gcount[cur], cnt);
}

__global__ __launch_bounds__(64) void mlp_head(const float* __restrict__ Zsum,
                                               const int* __restrict__ gcount,
                                               const float* __restrict__ Wh1,
                                               const float* __restrict__ bh1,
                                               const float* __restrict__ Wh2,
                                               const float* __restrict__ bh2,
                                               float* __restrict__ out) {
    __shared__ float sz[64];
    int g = blockIdx.x, tid = threadIdx.x;
    int cnt = gcount[g];
    float inv = 1.f / (float)(cnt > 1 ? cnt : 1);
    sz[tid] = Zsum[g * 64 + tid] * inv;
    __syncthreads();
    float acc = bh1[tid];
    #pragma unroll
    for (int c = 0; c < 64; c++) acc = fmaf(sz[c], Wh1[c * 64 + tid], acc);
    acc = fmaxf(acc, 0.f);
    float v = acc * Wh2[tid];
    #pragma unroll
    for (int off = 32; off > 0; off >>= 1) v += __shfl_xor(v, off, 64);
    if (tid == 0) out[g] = v + bh2[0];
}

// ---------------------------------------------------------------- launch
extern "C" void kernel_launch(void* const* d_in, const int* in_sizes, int n_in,
                              void* d_out, int out_size, void* d_ws, size_t ws_size,
                              hipStream_t stream) {
    (void)in_sizes; (void)n_in; (void)out_size; (void)ws_size;
    const float* x     = (const float*)d_in[0];
    const int*   ei    = (const int*)d_in[1];
    const int*   batch = (const int*)d_in[2];
    const float* Wl0 = (const float*)d_in[3];  const float* bl0 = (const float*)d_in[4];
    const float* Wr0 = (const float*)d_in[5];  const float* br0 = (const float*)d_in[6];
    const float* at0 = (const float*)d_in[7];  const float* bi0 = (const float*)d_in[8];
    const float* lg0 = (const float*)d_in[9];  const float* lb0 = (const float*)d_in[10];
    const float* Wl1 = (const float*)d_in[11]; const float* bl1 = (const float*)d_in[12];
    const float* Wr1 = (const float*)d_in[13]; const float* br1 = (const float*)d_in[14];
    const float* at1 = (const float*)d_in[15]; const float* bi1 = (const float*)d_in[16];
    const float* lg1 = (const float*)d_in[17]; const float* lb1 = (const float*)d_in[18];
    const float* Wl2 = (const float*)d_in[19]; const float* bl2 = (const float*)d_in[20];
    const float* Wr2 = (const float*)d_in[21]; const float* br2 = (const float*)d_in[22];
    const float* at2 = (const float*)d_in[23]; const float* bi2 = (const float*)d_in[24];
    const float* lg2 = (const float*)d_in[25]; const float* lb2 = (const float*)d_in[26];
    const float* Wh1 = (const float*)d_in[27]; const float* bh1 = (const float*)d_in[28];
    const float* Wh2 = (const float*)d_in[29]; const float* bh2 = (const float*)d_in[30];
    float* out = (float*)d_out;

    const int* srcp = ei;
    const int* dstp = ei + NE;

    char* w = (char*)d_ws;
    size_t off = 0;
    auto carve = [&](size_t bytes) -> void* {
        void* p = w + off;
        off += (bytes + 255) & ~(size_t)255;
        return p;
    };
    float* A = (float*)carve((size_t)NN * 256 * 4);   // xl
    float* B = (float*)carve((size_t)NN * 256 * 4);   // xr
    float* C = (float*)carve((size_t)NN * 256 * 4);   // h1 raw / h3 raw
    float* D = (float*)carve((size_t)NN * 64 * 4);    // h2 raw
    ushort* wt = (ushort*)carve(212992 * 2);          // split-bf16 transposed weights
    const size_t REDB = (size_t)3 * NBUCK * 2 * sizeof(double);   // 3 bucket sets
    size_t zbytes = REDB + (size_t)NG * 64 * 4 + NG * 4 + (size_t)NN * 4;
    char* zb = (char*)carve(zbytes);
    double* red   = (double*)zb;
    float*  Zsum  = (float*)(zb + REDB);
    int*    gcnt  = (int*)(zb + REDB + (size_t)NG * 64 * 4);
    int*    deg   = (int*)(zb + REDB + (size_t)NG * 64 * 4 + NG * 4);
    int* row_ptr = (int*)carve((size_t)(NN + 1) * 4);
    int* cursor  = (int*)carve((size_t)NN * 4);
    int* col_src = (int*)carve((size_t)NE * 4);
    int* bsum    = (int*)carve(64 * 4);

    const ushort* W0lh = wt;           const ushort* W0ll = wt + 32768;
    const ushort* W0rh = wt + 65536;   const ushort* W0rl = wt + 98304;
    const ushort* W1lh = wt + 131072;  const ushort* W1ll = wt + 147456;
    const ushort* W1rh = wt + 163840;  const ushort* W1rl = wt + 180224;
    const ushort* W2lh = wt + 196608;  const ushort* W2ll = wt + 200704;
    const ushort* W2rh = wt + 204800;  const ushort* W2rl = wt + 208896;

    hipMemsetAsync(zb, 0, zbytes, stream);
    prep_w<<<416, 256, 0, stream>>>(Wl0, Wr0, Wl1, Wr1, Wl2, Wr2, wt);

    // CSR build (sort edges by dst)
    hist_kernel<<<(NE + 255) / 256, 256, 0, stream>>>(dstp, deg);
    const int SB = (NN + 1023) / 1024;  // 49
    scan1<<<SB, 1024, 0, stream>>>(deg, row_ptr, bsum, NN);
    scan3<<<SB, 1024, 0, stream>>>(row_ptr, cursor, bsum, NN);
    scatter_kernel<<<(NE + 255) / 256, 256, 0, stream>>>(srcp, dstp, cursor, col_src);

    const int GR = (NN + 63) / 64;     // 782 (gemm row blocks)
    const int GATB = NN / 4;           // 12500 (4 nodes/block, wave-per-node)

    // ---- layer 0: 128 -> 4x64 (all 256 cols per block: A read once; dual via blockIdx.y)
    gemm_mfma<4, false, false><<<dim3(GR, 2), 256, 0, stream>>>(
        x, W0lh, W0ll, bl0, A, W0rh, W0rl, br0, B, NN, 256, 128,
        nullptr, 1, nullptr, nullptr);
    gat4<<<GATB, 256, 0, stream>>>(A, B, at0, bi0, row_ptr, col_src, C, red);

    // ---- layer 1: 256 -> 64 (dual-output single launch; LN0+ReLU fused into A-staging)
    gemm_mfma<2, true, true><<<dim3(GR), 256, 0, stream>>>(
        C, W1lh, W1ll, bl1, A, W1rh, W1rl, br1, B, NN, 64, 256,
        red, NN * 256, lg0, lb0);
    gat1<<<GATB, 256, 0, stream>>>(A, B, at1, bi1, row_ptr, col_src, D, red + 2 * NBUCK);

    // ---- layer 2: 64 -> 64 (dual-output single launch; LN1+ReLU fused into A-staging)
    gemm_mfma<2, true, true><<<dim3(GR), 256, 0, stream>>>(
        D, W2lh, W2ll, bl2, A, W2rh, W2rl, br2, B, NN, 64, 64,
        red + 2 * NBUCK, NN * 64, lg1, lb1);
    gat1<<<GATB, 256, 0, stream>>>(A, B, at2, bi2, row_ptr, col_src, C, red + 4 * NBUCK);

    // ---- pool (inline stats + fused LN+ReLU+residual, boundary-flush atomics) + MLP head
    pool_ln<<<PLB, 256, 0, stream>>>(C, D, red, lg1, lb1, lg2, lb2,
                                     batch, Zsum, gcnt);
    mlp_head<<<NG, 64, 0, stream>>>(Zsum, gcnt, Wh1, bh1, Wh2, bh2, out);
}